// Round 10
// baseline (1476.881 us; speedup 1.0000x reference)
//
#include <hip/hip_runtime.h>
#include <math.h>

#define FD 128
#define NOUT 16
#define ALPHA_F 0.1f

typedef short short8 __attribute__((ext_vector_type(8)));
typedef float f32x4 __attribute__((ext_vector_type(4)));
typedef unsigned uintx4 __attribute__((ext_vector_type(4)));

// ---------- bf16 helpers (bit-level, RNE) ----------
__device__ __forceinline__ float bflo(unsigned u) { return __uint_as_float(u << 16); }
__device__ __forceinline__ float bfhi(unsigned u) { return __uint_as_float(u & 0xffff0000u); }
__device__ __forceinline__ unsigned f2bf(float f) {
    unsigned u = __float_as_uint(f);
    u += 0x7fffu + ((u >> 16) & 1u);          // round-to-nearest-even
    return u >> 16;
}
__device__ __forceinline__ unsigned pack2(float a, float b) {
    return f2bf(a) | (f2bf(b) << 16);
}
// non-temporal helpers (keep streams out of L2 so the feature plane stays resident)
__device__ __forceinline__ uintx4 ntload4(const unsigned* p) {
    return __builtin_nontemporal_load((const uintx4*)p);
}
__device__ __forceinline__ unsigned ntload1(const unsigned* p) {
    return __builtin_nontemporal_load(p);
}
__device__ __forceinline__ void ntstore1(unsigned* p, unsigned v) {
    __builtin_nontemporal_store(v, p);
}

// ---------- CSC build ----------

__global__ void count_kernel(const int* __restrict__ cols, int* __restrict__ cnt, int e) {
    int i = blockIdx.x * blockDim.x + threadIdx.x;
    if (i < e) atomicAdd(&cnt[cols[i]], 1);
}

__global__ void dinv_kernel(const int* __restrict__ cnt, float* __restrict__ dinv, int n) {
    int i = blockIdx.x * blockDim.x + threadIdx.x;
    if (i < n) dinv[i] = rsqrtf((float)(cnt[i] + 1));   // +1 self-loop
}

// padded degree: true degree (cnt+1) rounded up to multiple of 8
__device__ __forceinline__ int padded(int cnt) { return (cnt + 8) & ~7; }

// three-kernel exclusive scan of padded degrees
__global__ void scan_partial_kernel(const int* __restrict__ cnt, int* __restrict__ bsum, int n) {
    __shared__ int sh[256];
    int base = blockIdx.x * 1024 + threadIdx.x * 4;
    int s = 0;
    #pragma unroll
    for (int j = 0; j < 4; ++j) { int i = base + j; if (i < n) s += padded(cnt[i]); }
    sh[threadIdx.x] = s; __syncthreads();
    for (int d = 128; d > 0; d >>= 1) {
        if ((int)threadIdx.x < d) sh[threadIdx.x] += sh[threadIdx.x + d];
        __syncthreads();
    }
    if (threadIdx.x == 0) bsum[blockIdx.x] = sh[0];
}

__global__ void scan_base_kernel(int* __restrict__ bsum, int* __restrict__ off, int nb, int n) {
    if (threadIdx.x == 0 && blockIdx.x == 0) {
        int run = 0;
        for (int b = 0; b < nb; ++b) { int t = bsum[b]; bsum[b] = run; run += t; }
        off[n] = run;
    }
}

// writes off[i] and cur[i]=off[i]. cnt and cur alias (read-before-write per thread).
__global__ void scan_final_kernel(const int* __restrict__ cnt, const int* __restrict__ bsum,
                                  int* __restrict__ off, int* __restrict__ cur, int n) {
    __shared__ int sh[256];
    int t = threadIdx.x;
    int base_i = blockIdx.x * 1024 + t * 4;
    int v[4]; int s = 0;
    #pragma unroll
    for (int j = 0; j < 4; ++j) { int i = base_i + j; v[j] = (i < n) ? padded(cnt[i]) : 0; s += v[j]; }
    sh[t] = s; __syncthreads();
    for (int d = 1; d < 256; d <<= 1) {
        int x = (t >= d) ? sh[t - d] : 0;
        __syncthreads();
        sh[t] += x;
        __syncthreads();
    }
    int excl = sh[t] - s + bsum[blockIdx.x];
    #pragma unroll
    for (int j = 0; j < 4; ++j) {
        int i = base_i + j;
        if (i < n) { off[i] = excl; cur[i] = excl; }
        excl += v[j];
    }
}

// edge record: low16 = src node id, high16 = bf16 weight
__global__ void fill_edges_kernel(const int* __restrict__ rows, const int* __restrict__ cols,
                                  const float* __restrict__ dinv, int* __restrict__ cur,
                                  unsigned* __restrict__ eg, int e) {
    int i = blockIdx.x * blockDim.x + threadIdx.x;
    if (i < e) {
        int r = rows[i];
        int c = cols[i];
        int pos = atomicAdd(&cur[c], 1);
        eg[pos] = (f2bf(dinv[r] * dinv[c]) << 16) | (unsigned)r;
    }
}

__global__ void fill_loops_kernel(const float* __restrict__ dinv, int* __restrict__ cur,
                                  unsigned* __restrict__ eg, int n) {
    int i = blockIdx.x * blockDim.x + threadIdx.x;
    if (i < n) {
        int pos = atomicAdd(&cur[i], 1);
        eg[pos] = (f2bf(dinv[i] * dinv[i]) << 16) | (unsigned)i;
    }
}

// ---------- pre-processing for MFMA GEMM ----------

// Wt[c][ku] = pack2(W[2ku][c], W[2ku+1][c]) : transposed, bf16-packed. 128x64 uints.
__global__ void wtrans_kernel(const float* __restrict__ W, unsigned* __restrict__ Wt) {
    int idx = blockIdx.x * 256 + threadIdx.x;
    if (idx < 128 * 64) {
        int c = idx >> 6, ku = idx & 63;
        Wt[idx] = pack2(W[(2 * ku) * FD + c], W[(2 * ku + 1) * FD + c]);
    }
}

// ---------- MFMA GEMM:  Y = X@W + b ; Ab = bf16(Y), Z0b = bf16(alpha*Y) ----------
// Outputs in PLANE layout: plane p (uints [16p,16p+16) of the row) is a
// contiguous [n][16]-uint array at offset p*n*16. K-step kk reads plane kk.
// BF_IN=0: A from fp32 row-major (stage 1); BF_IN=1: A from plane-layout bf16.
template <int BF_IN>
__global__ __launch_bounds__(256, 4)
void gemm_mfma_kernel(const void* __restrict__ Xv, const unsigned* __restrict__ Wt,
                      const float* __restrict__ bias,
                      unsigned* __restrict__ Ab, unsigned* __restrict__ Z0b, int n) {
    int l = threadIdx.x & 63;
    int w = threadIdx.x >> 6;
    int l15 = l & 15, lq = l >> 4;
    int r0 = blockIdx.x * 64 + w * 16;
    int arow = min(r0 + l15, n - 1);
    const unsigned* bptr = Wt + (size_t)l15 * 64 + lq * 4;
    const size_t pstride = (size_t)n * 16;

    f32x4 acc[8];
    #pragma unroll
    for (int nt = 0; nt < 8; ++nt) acc[nt] = (f32x4){0.f, 0.f, 0.f, 0.f};

    #pragma unroll
    for (int kk = 0; kk < 4; ++kk) {
        short8 af;
        if (BF_IN) {
            const unsigned* aptr = (const unsigned*)Xv + (size_t)kk * pstride
                                   + (size_t)arow * 16 + lq * 4;
            af = *(const short8*)aptr;
        } else {
            const float* ap = (const float*)Xv + (size_t)arow * FD + lq * 8 + kk * 32;
            float4 fa = *(const float4*)(ap);
            float4 fb = *(const float4*)(ap + 4);
            unsigned p0 = pack2(fa.x, fa.y), p1 = pack2(fa.z, fa.w);
            unsigned p2 = pack2(fb.x, fb.y), p3 = pack2(fb.z, fb.w);
            uint4 u = make_uint4(p0, p1, p2, p3);
            af = *(const short8*)&u;
        }
        #pragma unroll
        for (int nt = 0; nt < 8; ++nt) {
            short8 bf = *(const short8*)(bptr + nt * 1024 + kk * 16);
            acc[nt] = __builtin_amdgcn_mfma_f32_16x16x32_bf16(af, bf, acc[nt], 0, 0, 0);
        }
    }

    #pragma unroll
    for (int nt = 0; nt < 8; ++nt) {
        float b_ = bias[nt * 16 + l15];
        #pragma unroll
        for (int j = 0; j < 4; ++j) {
            float v = acc[nt][j] + b_;
            float vp = __shfl_xor(v, 1);
            int row = r0 + lq * 4 + j;
            if (!(l & 1) && row < n) {
                int cu = nt * 8 + (l15 >> 1);          // uint index 0..63
                size_t idx = (size_t)(cu >> 4) * pstride + (size_t)row * 16 + (cu & 15);
                Ab[idx]  = pack2(v, vp);
                Z0b[idx] = pack2(ALPHA_F * v, ALPHA_F * vp);
            }
        }
    }
}

// ---------- APPNP step, plane layout: Xout = 0.9*A_hat@Xin + Z0b ----------
// plane = blockIdx & 3; with the b%8 -> XCD round-robin, each XCD serves ONE
// plane: gather working set n*64B = 3.2 MB < 4 MB L2, no cache-line sharing
// across planes (planes are contiguous). Edge records / Z0 / output are
// non-temporal so they don't evict the plane. 16 lanes per node-slice
// (1 uint = 2 features per lane); 16 nodes per 256-thread block; padded
// degrees (zero-weight records) keep the loop branch-free; groups diverge
// naturally on their own trip counts.
__global__ __launch_bounds__(256, 8)
void spmm_plane_kernel(const int* __restrict__ off, const unsigned* __restrict__ eg,
                       const unsigned* __restrict__ Xin, const unsigned* __restrict__ X0b,
                       unsigned* __restrict__ Xout, int n, int relu) {
    int b = blockIdx.x;
    int plane = b & 3;
    int node = (b >> 2) * 16 + ((int)threadIdx.x >> 4);
    if (node >= n) return;
    int j = threadIdx.x & 15;
    const size_t pbase = (size_t)plane * n * 16;
    const unsigned* Xp = Xin + pbase;
    int s = off[node];
    int degpad = off[node + 1] - s;                    // multiple of 8, >= 8
    unsigned x0 = ntload1(X0b + pbase + (size_t)node * 16 + j);   // issue early
    const unsigned* ep = eg + s;
    float a0 = 0.f, a1 = 0.f;

    for (int c = 0; c < degpad; c += 8) {
        uintx4 ra = ntload4(ep + c);
        uintx4 rb = ntload4(ep + c + 4);
        unsigned g0 = Xp[(ra[0] & 0xffffu) * 16u + j];
        unsigned g1 = Xp[(ra[1] & 0xffffu) * 16u + j];
        unsigned g2 = Xp[(ra[2] & 0xffffu) * 16u + j];
        unsigned g3 = Xp[(ra[3] & 0xffffu) * 16u + j];
        unsigned g4 = Xp[(rb[0] & 0xffffu) * 16u + j];
        unsigned g5 = Xp[(rb[1] & 0xffffu) * 16u + j];
        unsigned g6 = Xp[(rb[2] & 0xffffu) * 16u + j];
        unsigned g7 = Xp[(rb[3] & 0xffffu) * 16u + j];
        float w0 = bfhi(ra[0]), w1 = bfhi(ra[1]), w2 = bfhi(ra[2]), w3 = bfhi(ra[3]);
        float w4 = bfhi(rb[0]), w5 = bfhi(rb[1]), w6 = bfhi(rb[2]), w7 = bfhi(rb[3]);
        a0 += w0 * bflo(g0); a1 += w0 * bfhi(g0);
        a0 += w1 * bflo(g1); a1 += w1 * bfhi(g1);
        a0 += w2 * bflo(g2); a1 += w2 * bfhi(g2);
        a0 += w3 * bflo(g3); a1 += w3 * bfhi(g3);
        a0 += w4 * bflo(g4); a1 += w4 * bfhi(g4);
        a0 += w5 * bflo(g5); a1 += w5 * bfhi(g5);
        a0 += w6 * bflo(g6); a1 += w6 * bfhi(g6);
        a0 += w7 * bflo(g7); a1 += w7 * bfhi(g7);
    }

    float v0 = 0.9f * a0 + bflo(x0);
    float v1 = 0.9f * a1 + bfhi(x0);
    if (relu) { v0 = fmaxf(v0, 0.f); v1 = fmaxf(v1, 0.f); }
    ntstore1(Xout + pbase + (size_t)node * 16 + j, pack2(v0, v1));
}

// ---------- head: logits = H @ Wc + bc ; log_softmax. 16 lanes/node ----------
// H in plane layout: plane p holds features [32p, 32p+32).
__global__ void head_kernel(const unsigned* __restrict__ Hb, const float* __restrict__ Wc,
                            const float* __restrict__ bc, float* __restrict__ out, int n) {
    int t = threadIdx.x;
    int o = t & (NOUT - 1);
    int node = blockIdx.x * (256 / NOUT) + (t >> 4);
    if (node >= n) return;
    const size_t pstride = (size_t)n * 16;
    float acc = bc[o];
    #pragma unroll
    for (int p = 0; p < 4; ++p) {
        const uint4* hp = (const uint4*)(Hb + (size_t)p * pstride + (size_t)node * 16);
        #pragma unroll
        for (int q = 0; q < 4; ++q) {
            uint4 u = hp[q];
            int k = p * 32 + q * 8;
            acc += bflo(u.x) * Wc[(k + 0) * NOUT + o];
            acc += bfhi(u.x) * Wc[(k + 1) * NOUT + o];
            acc += bflo(u.y) * Wc[(k + 2) * NOUT + o];
            acc += bfhi(u.y) * Wc[(k + 3) * NOUT + o];
            acc += bflo(u.z) * Wc[(k + 4) * NOUT + o];
            acc += bfhi(u.z) * Wc[(k + 5) * NOUT + o];
            acc += bflo(u.w) * Wc[(k + 6) * NOUT + o];
            acc += bfhi(u.w) * Wc[(k + 7) * NOUT + o];
        }
    }
    float m = acc;
    #pragma unroll
    for (int d = NOUT / 2; d > 0; d >>= 1) m = fmaxf(m, __shfl_xor(m, d, NOUT));
    float ex = __expf(acc - m);
    float s = ex;
    #pragma unroll
    for (int d = NOUT / 2; d > 0; d >>= 1) s += __shfl_xor(s, d, NOUT);
    out[node * NOUT + o] = acc - m - __logf(s);
}

// ---------- launch ----------

static inline size_t align256(size_t x) { return (x + 255) & ~(size_t)255; }

extern "C" void kernel_launch(void* const* d_in, const int* in_sizes, int n_in,
                              void* d_out, int out_size, void* d_ws, size_t ws_size,
                              hipStream_t stream) {
    const float* x  = (const float*)d_in[0];
    const int*   ei = (const int*)d_in[1];
    const float* W1 = (const float*)d_in[2];
    const float* b1 = (const float*)d_in[3];
    const float* W2 = (const float*)d_in[4];
    const float* b2 = (const float*)d_in[5];
    const float* W3 = (const float*)d_in[6];
    const float* b3 = (const float*)d_in[7];
    const float* Wc = (const float*)d_in[8];
    const float* bc = (const float*)d_in[9];
    float* out = (float*)d_out;

    const int n = in_sizes[0] / FD;       // 50000
    const int e = in_sizes[1] / 2;        // 800000
    const int nnz_max = e + n + 8 * n + 16;   // padded upper bound
    const int nb = (n + 1023) / 1024;

    const int* rows = ei;
    const int* cols = ei + e;

    // workspace layout (~57 MB)
    char* p = (char*)d_ws;
    int*      off  = (int*)p;       p += align256((size_t)(n + 1) * 4);
    int*      cur  = (int*)p;       p += align256((size_t)n * 4);
    float*    dinv = (float*)p;     p += align256((size_t)n * 4);
    int*      bsum = (int*)p;       p += align256((size_t)nb * 4);
    unsigned* eg   = (unsigned*)p;  p += align256((size_t)nnz_max * 4);
    unsigned* Wt   = (unsigned*)p;  p += align256((size_t)3 * 8192 * 4);
    unsigned* Ab   = (unsigned*)p;  p += align256((size_t)n * 64 * 4);
    unsigned* Bb   = (unsigned*)p;  p += align256((size_t)n * 64 * 4);
    unsigned* Z0b  = (unsigned*)p;  p += align256((size_t)n * 64 * 4);
    unsigned* Hb   = (unsigned*)p;  p += align256((size_t)n * 64 * 4);

    // ---- build padded CSC ----
    hipMemsetAsync(cur, 0, (size_t)n * 4, stream);
    hipMemsetAsync(eg, 0, (size_t)nnz_max * 4, stream);
    count_kernel<<<(e + 255) / 256, 256, 0, stream>>>(cols, cur, e);
    dinv_kernel<<<(n + 255) / 256, 256, 0, stream>>>(cur, dinv, n);
    scan_partial_kernel<<<nb, 256, 0, stream>>>(cur, bsum, n);
    scan_base_kernel<<<1, 64, 0, stream>>>(bsum, off, nb, n);
    scan_final_kernel<<<nb, 256, 0, stream>>>(cur, bsum, off, cur, n);
    fill_edges_kernel<<<(e + 255) / 256, 256, 0, stream>>>(rows, cols, dinv, cur, eg, e);
    fill_loops_kernel<<<(n + 255) / 256, 256, 0, stream>>>(dinv, cur, eg, n);

    // ---- weight transpose ----
    wtrans_kernel<<<32, 256, 0, stream>>>(W1, Wt);
    wtrans_kernel<<<32, 256, 0, stream>>>(W2, Wt + 8192);
    wtrans_kernel<<<32, 256, 0, stream>>>(W3, Wt + 16384);

    const int gemm_grid = (n + 63) / 64;
    const int spmm_grid = ((n + 15) / 16) * 4;    // 4 planes x node-chunks
    const float* bl[3] = { b1, b2, b3 };
    const void* gin = x;

    for (int st = 0; st < 3; ++st) {
        if (st == 0)
            gemm_mfma_kernel<0><<<gemm_grid, 256, 0, stream>>>(gin, Wt, bl[st], Ab, Z0b, n);
        else
            gemm_mfma_kernel<1><<<gemm_grid, 256, 0, stream>>>(gin, Wt + st * 8192, bl[st], Ab, Z0b, n);
        unsigned* bufs[2] = { Ab, Bb };
        int cu = 0;
        for (int k = 0; k < 10; ++k) {
            unsigned* o_ = (k == 9) ? Hb : bufs[cu ^ 1];
            spmm_plane_kernel<<<spmm_grid, 256, 0, stream>>>(off, eg, bufs[cu], Z0b, o_, n, k == 9);
            cu ^= 1;
        }
        gin = Hb;
    }

    head_kernel<<<(n + 15) / 16, 256, 0, stream>>>(Hb, Wc, bc, out, n);
}

// Round 11
// 1475.531 us; speedup vs baseline: 1.0009x; 1.0009x over previous
//
#include <hip/hip_runtime.h>
#include <math.h>

#define FD 128
#define NOUT 16
#define ALPHA_F 0.1f

typedef short short8 __attribute__((ext_vector_type(8)));
typedef float f32x4 __attribute__((ext_vector_type(4)));
typedef unsigned uintx4 __attribute__((ext_vector_type(4)));
typedef unsigned uintx2 __attribute__((ext_vector_type(2)));

// ---------- bf16 helpers (bit-level, RNE) ----------
__device__ __forceinline__ float bflo(unsigned u) { return __uint_as_float(u << 16); }
__device__ __forceinline__ float bfhi(unsigned u) { return __uint_as_float(u & 0xffff0000u); }
__device__ __forceinline__ unsigned f2bf(float f) {
    unsigned u = __float_as_uint(f);
    u += 0x7fffu + ((u >> 16) & 1u);          // round-to-nearest-even
    return u >> 16;
}
__device__ __forceinline__ unsigned pack2(float a, float b) {
    return f2bf(a) | (f2bf(b) << 16);
}
// non-temporal helpers (keep streams out of L2 so the feature plane stays resident)
__device__ __forceinline__ uintx4 ntload4(const unsigned* p) {
    return __builtin_nontemporal_load((const uintx4*)p);
}
__device__ __forceinline__ uintx2 ntload2(const unsigned* p) {
    return __builtin_nontemporal_load((const uintx2*)p);
}
__device__ __forceinline__ void ntstore2(unsigned* p, uintx2 v) {
    __builtin_nontemporal_store(v, (uintx2*)p);
}

// ---------- CSC build ----------

__global__ void count_kernel(const int* __restrict__ cols, int* __restrict__ cnt, int e) {
    int i = blockIdx.x * blockDim.x + threadIdx.x;
    if (i < e) atomicAdd(&cnt[cols[i]], 1);
}

__global__ void dinv_kernel(const int* __restrict__ cnt, float* __restrict__ dinv, int n) {
    int i = blockIdx.x * blockDim.x + threadIdx.x;
    if (i < n) dinv[i] = rsqrtf((float)(cnt[i] + 1));   // +1 self-loop
}

// padded degree: true degree (cnt+1) rounded up to multiple of 8
__device__ __forceinline__ int padded(int cnt) { return (cnt + 8) & ~7; }

// three-kernel exclusive scan of padded degrees
__global__ void scan_partial_kernel(const int* __restrict__ cnt, int* __restrict__ bsum, int n) {
    __shared__ int sh[256];
    int base = blockIdx.x * 1024 + threadIdx.x * 4;
    int s = 0;
    #pragma unroll
    for (int j = 0; j < 4; ++j) { int i = base + j; if (i < n) s += padded(cnt[i]); }
    sh[threadIdx.x] = s; __syncthreads();
    for (int d = 128; d > 0; d >>= 1) {
        if ((int)threadIdx.x < d) sh[threadIdx.x] += sh[threadIdx.x + d];
        __syncthreads();
    }
    if (threadIdx.x == 0) bsum[blockIdx.x] = sh[0];
}

__global__ void scan_base_kernel(int* __restrict__ bsum, int* __restrict__ off, int nb, int n) {
    if (threadIdx.x == 0 && blockIdx.x == 0) {
        int run = 0;
        for (int b = 0; b < nb; ++b) { int t = bsum[b]; bsum[b] = run; run += t; }
        off[n] = run;
    }
}

// writes off[i] and cur[i]=off[i]. cnt and cur alias (read-before-write per thread).
__global__ void scan_final_kernel(const int* __restrict__ cnt, const int* __restrict__ bsum,
                                  int* __restrict__ off, int* __restrict__ cur, int n) {
    __shared__ int sh[256];
    int t = threadIdx.x;
    int base_i = blockIdx.x * 1024 + t * 4;
    int v[4]; int s = 0;
    #pragma unroll
    for (int j = 0; j < 4; ++j) { int i = base_i + j; v[j] = (i < n) ? padded(cnt[i]) : 0; s += v[j]; }
    sh[t] = s; __syncthreads();
    for (int d = 1; d < 256; d <<= 1) {
        int x = (t >= d) ? sh[t - d] : 0;
        __syncthreads();
        sh[t] += x;
        __syncthreads();
    }
    int excl = sh[t] - s + bsum[blockIdx.x];
    #pragma unroll
    for (int j = 0; j < 4; ++j) {
        int i = base_i + j;
        if (i < n) { off[i] = excl; cur[i] = excl; }
        excl += v[j];
    }
}

// edge record: low16 = src node id, high16 = bf16 weight
__global__ void fill_edges_kernel(const int* __restrict__ rows, const int* __restrict__ cols,
                                  const float* __restrict__ dinv, int* __restrict__ cur,
                                  unsigned* __restrict__ eg, int e) {
    int i = blockIdx.x * blockDim.x + threadIdx.x;
    if (i < e) {
        int r = rows[i];
        int c = cols[i];
        int pos = atomicAdd(&cur[c], 1);
        eg[pos] = (f2bf(dinv[r] * dinv[c]) << 16) | (unsigned)r;
    }
}

__global__ void fill_loops_kernel(const float* __restrict__ dinv, int* __restrict__ cur,
                                  unsigned* __restrict__ eg, int n) {
    int i = blockIdx.x * blockDim.x + threadIdx.x;
    if (i < n) {
        int pos = atomicAdd(&cur[i], 1);
        eg[pos] = (f2bf(dinv[i] * dinv[i]) << 16) | (unsigned)i;
    }
}

// ---------- pre-processing for MFMA GEMM ----------

// Wt[c][ku] = pack2(W[2ku][c], W[2ku+1][c]) : transposed, bf16-packed. 128x64 uints.
__global__ void wtrans_kernel(const float* __restrict__ W, unsigned* __restrict__ Wt) {
    int idx = blockIdx.x * 256 + threadIdx.x;
    if (idx < 128 * 64) {
        int c = idx >> 6, ku = idx & 63;
        Wt[idx] = pack2(W[(2 * ku) * FD + c], W[(2 * ku + 1) * FD + c]);
    }
}

// ---------- MFMA GEMM:  Y = X@W + b ; Ab = bf16(Y), Z0b = bf16(alpha*Y) ----------
// Outputs in PLANE layout: plane p (uints [16p,16p+16) of the row) is a
// contiguous [n][16]-uint array at offset p*n*16. K-step kk reads plane kk.
// BF_IN=0: A from fp32 row-major (stage 1); BF_IN=1: A from plane-layout bf16.
template <int BF_IN>
__global__ __launch_bounds__(256, 4)
void gemm_mfma_kernel(const void* __restrict__ Xv, const unsigned* __restrict__ Wt,
                      const float* __restrict__ bias,
                      unsigned* __restrict__ Ab, unsigned* __restrict__ Z0b, int n) {
    int l = threadIdx.x & 63;
    int w = threadIdx.x >> 6;
    int l15 = l & 15, lq = l >> 4;
    int r0 = blockIdx.x * 64 + w * 16;
    int arow = min(r0 + l15, n - 1);
    const unsigned* bptr = Wt + (size_t)l15 * 64 + lq * 4;
    const size_t pstride = (size_t)n * 16;

    f32x4 acc[8];
    #pragma unroll
    for (int nt = 0; nt < 8; ++nt) acc[nt] = (f32x4){0.f, 0.f, 0.f, 0.f};

    #pragma unroll
    for (int kk = 0; kk < 4; ++kk) {
        short8 af;
        if (BF_IN) {
            const unsigned* aptr = (const unsigned*)Xv + (size_t)kk * pstride
                                   + (size_t)arow * 16 + lq * 4;
            af = *(const short8*)aptr;
        } else {
            const float* ap = (const float*)Xv + (size_t)arow * FD + lq * 8 + kk * 32;
            float4 fa = *(const float4*)(ap);
            float4 fb = *(const float4*)(ap + 4);
            unsigned p0 = pack2(fa.x, fa.y), p1 = pack2(fa.z, fa.w);
            unsigned p2 = pack2(fb.x, fb.y), p3 = pack2(fb.z, fb.w);
            uint4 u = make_uint4(p0, p1, p2, p3);
            af = *(const short8*)&u;
        }
        #pragma unroll
        for (int nt = 0; nt < 8; ++nt) {
            short8 bf = *(const short8*)(bptr + nt * 1024 + kk * 16);
            acc[nt] = __builtin_amdgcn_mfma_f32_16x16x32_bf16(af, bf, acc[nt], 0, 0, 0);
        }
    }

    #pragma unroll
    for (int nt = 0; nt < 8; ++nt) {
        float b_ = bias[nt * 16 + l15];
        #pragma unroll
        for (int j = 0; j < 4; ++j) {
            float v = acc[nt][j] + b_;
            float vp = __shfl_xor(v, 1);
            int row = r0 + lq * 4 + j;
            if (!(l & 1) && row < n) {
                int cu = nt * 8 + (l15 >> 1);          // uint index 0..63
                size_t idx = (size_t)(cu >> 4) * pstride + (size_t)row * 16 + (cu & 15);
                Ab[idx]  = pack2(v, vp);
                Z0b[idx] = pack2(ALPHA_F * v, ALPHA_F * vp);
            }
        }
    }
}

// ---------- APPNP step, plane layout + wide gathers ----------
// plane = blockIdx & 3; with the b%8 -> XCD round-robin each XCD serves ONE
// plane (XCD x -> plane x%4): gather working set n*64B = 3.2 MB < 4 MB L2.
// 8 lanes per node (uint2 = 4 features each, full 64 B plane row), 8 nodes
// per wave -> each gather instruction moves 512 B, all L2-hits (R5's
// instruction shape + R10's residency). Records broadcast within the 8-lane
// group; edge/Z0/out streams non-temporal so the plane stays resident.
__global__ __launch_bounds__(256, 8)
void spmm_plane_kernel(const int* __restrict__ off, const unsigned* __restrict__ eg,
                       const unsigned* __restrict__ Xin, const unsigned* __restrict__ X0b,
                       unsigned* __restrict__ Xout, int n, int relu) {
    int b = blockIdx.x;
    int plane = b & 3;
    int node = (b >> 2) * 32 + ((int)threadIdx.x >> 3);
    if (node >= n) return;
    int j = threadIdx.x & 7;                       // uint2 index within plane row
    const size_t pu2 = (size_t)plane * n * 8;      // plane base in uint2 units
    const uint2* Xp = (const uint2*)Xin + pu2;
    int s = off[node];
    int degpad = off[node + 1] - s;                // multiple of 8, >= 8
    uintx2 x0 = ntload2(X0b + 2 * (pu2 + (size_t)node * 8 + j));   // issue early
    const unsigned* ep = eg + s;
    float a0 = 0.f, a1 = 0.f, a2 = 0.f, a3 = 0.f;

    for (int c = 0; c < degpad; c += 8) {
        uintx4 ra = ntload4(ep + c);               // broadcast within group
        uintx4 rb = ntload4(ep + c + 4);
        uint2 g0 = Xp[(ra[0] & 0xffffu) * 8u + j];
        uint2 g1 = Xp[(ra[1] & 0xffffu) * 8u + j];
        uint2 g2 = Xp[(ra[2] & 0xffffu) * 8u + j];
        uint2 g3 = Xp[(ra[3] & 0xffffu) * 8u + j];
        uint2 g4 = Xp[(rb[0] & 0xffffu) * 8u + j];
        uint2 g5 = Xp[(rb[1] & 0xffffu) * 8u + j];
        uint2 g6 = Xp[(rb[2] & 0xffffu) * 8u + j];
        uint2 g7 = Xp[(rb[3] & 0xffffu) * 8u + j];
        float w0 = bfhi(ra[0]), w1 = bfhi(ra[1]), w2 = bfhi(ra[2]), w3 = bfhi(ra[3]);
        float w4 = bfhi(rb[0]), w5 = bfhi(rb[1]), w6 = bfhi(rb[2]), w7 = bfhi(rb[3]);
        a0 += w0 * bflo(g0.x); a1 += w0 * bfhi(g0.x); a2 += w0 * bflo(g0.y); a3 += w0 * bfhi(g0.y);
        a0 += w1 * bflo(g1.x); a1 += w1 * bfhi(g1.x); a2 += w1 * bflo(g1.y); a3 += w1 * bfhi(g1.y);
        a0 += w2 * bflo(g2.x); a1 += w2 * bfhi(g2.x); a2 += w2 * bflo(g2.y); a3 += w2 * bfhi(g2.y);
        a0 += w3 * bflo(g3.x); a1 += w3 * bfhi(g3.x); a2 += w3 * bflo(g3.y); a3 += w3 * bfhi(g3.y);
        a0 += w4 * bflo(g4.x); a1 += w4 * bfhi(g4.x); a2 += w4 * bflo(g4.y); a3 += w4 * bfhi(g4.y);
        a0 += w5 * bflo(g5.x); a1 += w5 * bfhi(g5.x); a2 += w5 * bflo(g5.y); a3 += w5 * bfhi(g5.y);
        a0 += w6 * bflo(g6.x); a1 += w6 * bfhi(g6.x); a2 += w6 * bflo(g6.y); a3 += w6 * bfhi(g6.y);
        a0 += w7 * bflo(g7.x); a1 += w7 * bfhi(g7.x); a2 += w7 * bflo(g7.y); a3 += w7 * bfhi(g7.y);
    }

    float v0 = 0.9f * a0 + bflo(x0[0]);
    float v1 = 0.9f * a1 + bfhi(x0[0]);
    float v2 = 0.9f * a2 + bflo(x0[1]);
    float v3 = 0.9f * a3 + bfhi(x0[1]);
    if (relu) {
        v0 = fmaxf(v0, 0.f); v1 = fmaxf(v1, 0.f);
        v2 = fmaxf(v2, 0.f); v3 = fmaxf(v3, 0.f);
    }
    uintx2 o; o[0] = pack2(v0, v1); o[1] = pack2(v2, v3);
    ntstore2(Xout + 2 * (pu2 + (size_t)node * 8 + j), o);
}

// ---------- head: logits = H @ Wc + bc ; log_softmax. 16 lanes/node ----------
// H in plane layout: plane p holds features [32p, 32p+32).
__global__ void head_kernel(const unsigned* __restrict__ Hb, const float* __restrict__ Wc,
                            const float* __restrict__ bc, float* __restrict__ out, int n) {
    int t = threadIdx.x;
    int o = t & (NOUT - 1);
    int node = blockIdx.x * (256 / NOUT) + (t >> 4);
    if (node >= n) return;
    const size_t pstride = (size_t)n * 16;
    float acc = bc[o];
    #pragma unroll
    for (int p = 0; p < 4; ++p) {
        const uint4* hp = (const uint4*)(Hb + (size_t)p * pstride + (size_t)node * 16);
        #pragma unroll
        for (int q = 0; q < 4; ++q) {
            uint4 u = hp[q];
            int k = p * 32 + q * 8;
            acc += bflo(u.x) * Wc[(k + 0) * NOUT + o];
            acc += bfhi(u.x) * Wc[(k + 1) * NOUT + o];
            acc += bflo(u.y) * Wc[(k + 2) * NOUT + o];
            acc += bfhi(u.y) * Wc[(k + 3) * NOUT + o];
            acc += bflo(u.z) * Wc[(k + 4) * NOUT + o];
            acc += bfhi(u.z) * Wc[(k + 5) * NOUT + o];
            acc += bflo(u.w) * Wc[(k + 6) * NOUT + o];
            acc += bfhi(u.w) * Wc[(k + 7) * NOUT + o];
        }
    }
    float m = acc;
    #pragma unroll
    for (int d = NOUT / 2; d > 0; d >>= 1) m = fmaxf(m, __shfl_xor(m, d, NOUT));
    float ex = __expf(acc - m);
    float s = ex;
    #pragma unroll
    for (int d = NOUT / 2; d > 0; d >>= 1) s += __shfl_xor(s, d, NOUT);
    out[node * NOUT + o] = acc - m - __logf(s);
}

// ---------- launch ----------

static inline size_t align256(size_t x) { return (x + 255) & ~(size_t)255; }

extern "C" void kernel_launch(void* const* d_in, const int* in_sizes, int n_in,
                              void* d_out, int out_size, void* d_ws, size_t ws_size,
                              hipStream_t stream) {
    const float* x  = (const float*)d_in[0];
    const int*   ei = (const int*)d_in[1];
    const float* W1 = (const float*)d_in[2];
    const float* b1 = (const float*)d_in[3];
    const float* W2 = (const float*)d_in[4];
    const float* b2 = (const float*)d_in[5];
    const float* W3 = (const float*)d_in[6];
    const float* b3 = (const float*)d_in[7];
    const float* Wc = (const float*)d_in[8];
    const float* bc = (const float*)d_in[9];
    float* out = (float*)d_out;

    const int n = in_sizes[0] / FD;       // 50000
    const int e = in_sizes[1] / 2;        // 800000
    const int nnz_max = e + n + 8 * n + 16;   // padded upper bound
    const int nb = (n + 1023) / 1024;

    const int* rows = ei;
    const int* cols = ei + e;

    // workspace layout (~57 MB)
    char* p = (char*)d_ws;
    int*      off  = (int*)p;       p += align256((size_t)(n + 1) * 4);
    int*      cur  = (int*)p;       p += align256((size_t)n * 4);
    float*    dinv = (float*)p;     p += align256((size_t)n * 4);
    int*      bsum = (int*)p;       p += align256((size_t)nb * 4);
    unsigned* eg   = (unsigned*)p;  p += align256((size_t)nnz_max * 4);
    unsigned* Wt   = (unsigned*)p;  p += align256((size_t)3 * 8192 * 4);
    unsigned* Ab   = (unsigned*)p;  p += align256((size_t)n * 64 * 4);
    unsigned* Bb   = (unsigned*)p;  p += align256((size_t)n * 64 * 4);
    unsigned* Z0b  = (unsigned*)p;  p += align256((size_t)n * 64 * 4);
    unsigned* Hb   = (unsigned*)p;  p += align256((size_t)n * 64 * 4);

    // ---- build padded CSC ----
    hipMemsetAsync(cur, 0, (size_t)n * 4, stream);
    hipMemsetAsync(eg, 0, (size_t)nnz_max * 4, stream);
    count_kernel<<<(e + 255) / 256, 256, 0, stream>>>(cols, cur, e);
    dinv_kernel<<<(n + 255) / 256, 256, 0, stream>>>(cur, dinv, n);
    scan_partial_kernel<<<nb, 256, 0, stream>>>(cur, bsum, n);
    scan_base_kernel<<<1, 64, 0, stream>>>(bsum, off, nb, n);
    scan_final_kernel<<<nb, 256, 0, stream>>>(cur, bsum, off, cur, n);
    fill_edges_kernel<<<(e + 255) / 256, 256, 0, stream>>>(rows, cols, dinv, cur, eg, e);
    fill_loops_kernel<<<(n + 255) / 256, 256, 0, stream>>>(dinv, cur, eg, n);

    // ---- weight transpose ----
    wtrans_kernel<<<32, 256, 0, stream>>>(W1, Wt);
    wtrans_kernel<<<32, 256, 0, stream>>>(W2, Wt + 8192);
    wtrans_kernel<<<32, 256, 0, stream>>>(W3, Wt + 16384);

    const int gemm_grid = (n + 63) / 64;
    const int spmm_grid = ((n + 31) / 32) * 4;    // 4 planes x 32-node chunks
    const float* bl[3] = { b1, b2, b3 };
    const void* gin = x;

    for (int st = 0; st < 3; ++st) {
        if (st == 0)
            gemm_mfma_kernel<0><<<gemm_grid, 256, 0, stream>>>(gin, Wt, bl[st], Ab, Z0b, n);
        else
            gemm_mfma_kernel<1><<<gemm_grid, 256, 0, stream>>>(gin, Wt + st * 8192, bl[st], Ab, Z0b, n);
        unsigned* bufs[2] = { Ab, Bb };
        int cu = 0;
        for (int k = 0; k < 10; ++k) {
            unsigned* o_ = (k == 9) ? Hb : bufs[cu ^ 1];
            spmm_plane_kernel<<<spmm_grid, 256, 0, stream>>>(off, eg, bufs[cu], Z0b, o_, n, k == 9);
            cu ^= 1;
        }
        gin = Hb;
    }

    head_kernel<<<(n + 15) / 16, 256, 0, stream>>>(Hb, Wc, bc, out, n);
}

// Round 12
// 1195.657 us; speedup vs baseline: 1.2352x; 1.2341x over previous
//
#include <hip/hip_runtime.h>
#include <math.h>

#define FD 128
#define NOUT 16
#define ALPHA_F 0.1f

typedef short short8 __attribute__((ext_vector_type(8)));
typedef float f32x4 __attribute__((ext_vector_type(4)));
typedef unsigned uintx2 __attribute__((ext_vector_type(2)));

// ---------- bf16 helpers (bit-level, RNE) ----------
__device__ __forceinline__ float bflo(unsigned u) { return __uint_as_float(u << 16); }
__device__ __forceinline__ float bfhi(unsigned u) { return __uint_as_float(u & 0xffff0000u); }
__device__ __forceinline__ unsigned f2bf(float f) {
    unsigned u = __float_as_uint(f);
    u += 0x7fffu + ((u >> 16) & 1u);          // round-to-nearest-even
    return u >> 16;
}
__device__ __forceinline__ unsigned pack2(float a, float b) {
    return f2bf(a) | (f2bf(b) << 16);
}
// nt only for touch-once streams (Z0 read, output write) — NOT for edge records
__device__ __forceinline__ uintx2 ntload2(const unsigned* p) {
    return __builtin_nontemporal_load((const uintx2*)p);
}
__device__ __forceinline__ void ntstore2(unsigned* p, uintx2 v) {
    __builtin_nontemporal_store(v, (uintx2*)p);
}

// ---------- CSC build ----------

__global__ void count_kernel(const int* __restrict__ cols, int* __restrict__ cnt, int e) {
    int i = blockIdx.x * blockDim.x + threadIdx.x;
    if (i < e) atomicAdd(&cnt[cols[i]], 1);
}

__global__ void dinv_kernel(const int* __restrict__ cnt, float* __restrict__ dinv, int n) {
    int i = blockIdx.x * blockDim.x + threadIdx.x;
    if (i < n) dinv[i] = rsqrtf((float)(cnt[i] + 1));   // +1 self-loop
}

// padded degree: true degree (cnt+1) rounded up to multiple of 8
__device__ __forceinline__ int padded(int cnt) { return (cnt + 8) & ~7; }

// three-kernel exclusive scan of padded degrees
__global__ void scan_partial_kernel(const int* __restrict__ cnt, int* __restrict__ bsum, int n) {
    __shared__ int sh[256];
    int base = blockIdx.x * 1024 + threadIdx.x * 4;
    int s = 0;
    #pragma unroll
    for (int j = 0; j < 4; ++j) { int i = base + j; if (i < n) s += padded(cnt[i]); }
    sh[threadIdx.x] = s; __syncthreads();
    for (int d = 128; d > 0; d >>= 1) {
        if ((int)threadIdx.x < d) sh[threadIdx.x] += sh[threadIdx.x + d];
        __syncthreads();
    }
    if (threadIdx.x == 0) bsum[blockIdx.x] = sh[0];
}

__global__ void scan_base_kernel(int* __restrict__ bsum, int* __restrict__ off, int nb, int n) {
    if (threadIdx.x == 0 && blockIdx.x == 0) {
        int run = 0;
        for (int b = 0; b < nb; ++b) { int t = bsum[b]; bsum[b] = run; run += t; }
        off[n] = run;
    }
}

// writes off[i] and cur[i]=off[i]. cnt and cur alias (read-before-write per thread).
__global__ void scan_final_kernel(const int* __restrict__ cnt, const int* __restrict__ bsum,
                                  int* __restrict__ off, int* __restrict__ cur, int n) {
    __shared__ int sh[256];
    int t = threadIdx.x;
    int base_i = blockIdx.x * 1024 + t * 4;
    int v[4]; int s = 0;
    #pragma unroll
    for (int j = 0; j < 4; ++j) { int i = base_i + j; v[j] = (i < n) ? padded(cnt[i]) : 0; s += v[j]; }
    sh[t] = s; __syncthreads();
    for (int d = 1; d < 256; d <<= 1) {
        int x = (t >= d) ? sh[t - d] : 0;
        __syncthreads();
        sh[t] += x;
        __syncthreads();
    }
    int excl = sh[t] - s + bsum[blockIdx.x];
    #pragma unroll
    for (int j = 0; j < 4; ++j) {
        int i = base_i + j;
        if (i < n) { off[i] = excl; cur[i] = excl; }
        excl += v[j];
    }
}

// edge record: low16 = src node id, high16 = bf16 weight
__global__ void fill_edges_kernel(const int* __restrict__ rows, const int* __restrict__ cols,
                                  const float* __restrict__ dinv, int* __restrict__ cur,
                                  unsigned* __restrict__ eg, int e) {
    int i = blockIdx.x * blockDim.x + threadIdx.x;
    if (i < e) {
        int r = rows[i];
        int c = cols[i];
        int pos = atomicAdd(&cur[c], 1);
        eg[pos] = (f2bf(dinv[r] * dinv[c]) << 16) | (unsigned)r;
    }
}

__global__ void fill_loops_kernel(const float* __restrict__ dinv, int* __restrict__ cur,
                                  unsigned* __restrict__ eg, int n) {
    int i = blockIdx.x * blockDim.x + threadIdx.x;
    if (i < n) {
        int pos = atomicAdd(&cur[i], 1);
        eg[pos] = (f2bf(dinv[i] * dinv[i]) << 16) | (unsigned)i;
    }
}

// ---------- pre-processing for MFMA GEMM ----------

// Wt[c][ku] = pack2(W[2ku][c], W[2ku+1][c]) : transposed, bf16-packed. 128x64 uints.
__global__ void wtrans_kernel(const float* __restrict__ W, unsigned* __restrict__ Wt) {
    int idx = blockIdx.x * 256 + threadIdx.x;
    if (idx < 128 * 64) {
        int c = idx >> 6, ku = idx & 63;
        Wt[idx] = pack2(W[(2 * ku) * FD + c], W[(2 * ku + 1) * FD + c]);
    }
}

// ---------- MFMA GEMM:  Y = X@W + b ; Ab = bf16(Y), Z0b = bf16(alpha*Y) ----------
// Outputs in PLANE layout: plane p (uints [16p,16p+16) of the row) is a
// contiguous [n][16]-uint array at offset p*n*16. K-step kk reads plane kk.
template <int BF_IN>
__global__ __launch_bounds__(256, 4)
void gemm_mfma_kernel(const void* __restrict__ Xv, const unsigned* __restrict__ Wt,
                      const float* __restrict__ bias,
                      unsigned* __restrict__ Ab, unsigned* __restrict__ Z0b, int n) {
    int l = threadIdx.x & 63;
    int w = threadIdx.x >> 6;
    int l15 = l & 15, lq = l >> 4;
    int r0 = blockIdx.x * 64 + w * 16;
    int arow = min(r0 + l15, n - 1);
    const unsigned* bptr = Wt + (size_t)l15 * 64 + lq * 4;
    const size_t pstride = (size_t)n * 16;

    f32x4 acc[8];
    #pragma unroll
    for (int nt = 0; nt < 8; ++nt) acc[nt] = (f32x4){0.f, 0.f, 0.f, 0.f};

    #pragma unroll
    for (int kk = 0; kk < 4; ++kk) {
        short8 af;
        if (BF_IN) {
            const unsigned* aptr = (const unsigned*)Xv + (size_t)kk * pstride
                                   + (size_t)arow * 16 + lq * 4;
            af = *(const short8*)aptr;
        } else {
            const float* ap = (const float*)Xv + (size_t)arow * FD + lq * 8 + kk * 32;
            float4 fa = *(const float4*)(ap);
            float4 fb = *(const float4*)(ap + 4);
            unsigned p0 = pack2(fa.x, fa.y), p1 = pack2(fa.z, fa.w);
            unsigned p2 = pack2(fb.x, fb.y), p3 = pack2(fb.z, fb.w);
            uint4 u = make_uint4(p0, p1, p2, p3);
            af = *(const short8*)&u;
        }
        #pragma unroll
        for (int nt = 0; nt < 8; ++nt) {
            short8 bf = *(const short8*)(bptr + nt * 1024 + kk * 16);
            acc[nt] = __builtin_amdgcn_mfma_f32_16x16x32_bf16(af, bf, acc[nt], 0, 0, 0);
        }
    }

    #pragma unroll
    for (int nt = 0; nt < 8; ++nt) {
        float b_ = bias[nt * 16 + l15];
        #pragma unroll
        for (int j = 0; j < 4; ++j) {
            float v = acc[nt][j] + b_;
            float vp = __shfl_xor(v, 1);
            int row = r0 + lq * 4 + j;
            if (!(l & 1) && row < n) {
                int cu = nt * 8 + (l15 >> 1);          // uint index 0..63
                size_t idx = (size_t)(cu >> 4) * pstride + (size_t)row * 16 + (cu & 15);
                Ab[idx]  = pack2(v, vp);
                Z0b[idx] = pack2(ALPHA_F * v, ALPHA_F * vp);
            }
        }
    }
}

// ---------- APPNP step, plane layout + wide gathers + record prefetch ----------
// plane = blockIdx & 3; with the b%8 -> XCD round-robin each XCD serves ONE
// plane: gather working set n*64B = 3.2 MB < 4 MB L2. 8 lanes per node
// (uint2 = 4 features), 8 nodes per wave -> 512 B per gather instruction.
// Edge records are CACHED (sequential, 4 chunks per 128B line) and prefetched
// one chunk ahead so any miss overlaps the current chunk's gathers.
__global__ __launch_bounds__(256, 8)
void spmm_plane_kernel(const int* __restrict__ off, const unsigned* __restrict__ eg,
                       const unsigned* __restrict__ Xin, const unsigned* __restrict__ X0b,
                       unsigned* __restrict__ Xout, int n, int relu) {
    int b = blockIdx.x;
    int plane = b & 3;
    int node = (b >> 2) * 32 + ((int)threadIdx.x >> 3);
    if (node >= n) return;
    int j = threadIdx.x & 7;                       // uint2 index within plane row
    const size_t pu2 = (size_t)plane * n * 8;      // plane base in uint2 units
    const uint2* Xp = (const uint2*)Xin + pu2;
    int s = off[node];
    int degpad = off[node + 1] - s;                // multiple of 8, >= 8
    int nch = degpad >> 3;                         // >= 1 chunks of 8 edges
    uintx2 x0 = ntload2(X0b + 2 * (pu2 + (size_t)node * 8 + j));   // issue early
    const uint4* ep = (const uint4*)(eg + s);      // 32B-aligned (s mult of 8)
    float a0 = 0.f, a1 = 0.f, a2 = 0.f, a3 = 0.f;

    uint4 ra = ep[0], rb = ep[1];                  // chunk 0 records
    for (int k = 0; k < nch; ++k) {
        uint4 na = ra, nb2 = rb;
        if (k + 1 < nch) { na = ep[2 * k + 2]; nb2 = ep[2 * k + 3]; }  // prefetch
        uint2 g0 = Xp[(ra.x & 0xffffu) * 8u + j];
        uint2 g1 = Xp[(ra.y & 0xffffu) * 8u + j];
        uint2 g2 = Xp[(ra.z & 0xffffu) * 8u + j];
        uint2 g3 = Xp[(ra.w & 0xffffu) * 8u + j];
        uint2 g4 = Xp[(rb.x & 0xffffu) * 8u + j];
        uint2 g5 = Xp[(rb.y & 0xffffu) * 8u + j];
        uint2 g6 = Xp[(rb.z & 0xffffu) * 8u + j];
        uint2 g7 = Xp[(rb.w & 0xffffu) * 8u + j];
        float w0 = bfhi(ra.x), w1 = bfhi(ra.y), w2 = bfhi(ra.z), w3 = bfhi(ra.w);
        float w4 = bfhi(rb.x), w5 = bfhi(rb.y), w6 = bfhi(rb.z), w7 = bfhi(rb.w);
        a0 += w0 * bflo(g0.x); a1 += w0 * bfhi(g0.x); a2 += w0 * bflo(g0.y); a3 += w0 * bfhi(g0.y);
        a0 += w1 * bflo(g1.x); a1 += w1 * bfhi(g1.x); a2 += w1 * bflo(g1.y); a3 += w1 * bfhi(g1.y);
        a0 += w2 * bflo(g2.x); a1 += w2 * bfhi(g2.x); a2 += w2 * bflo(g2.y); a3 += w2 * bfhi(g2.y);
        a0 += w3 * bflo(g3.x); a1 += w3 * bfhi(g3.x); a2 += w3 * bflo(g3.y); a3 += w3 * bfhi(g3.y);
        a0 += w4 * bflo(g4.x); a1 += w4 * bfhi(g4.x); a2 += w4 * bflo(g4.y); a3 += w4 * bfhi(g4.y);
        a0 += w5 * bflo(g5.x); a1 += w5 * bfhi(g5.x); a2 += w5 * bflo(g5.y); a3 += w5 * bfhi(g5.y);
        a0 += w6 * bflo(g6.x); a1 += w6 * bfhi(g6.x); a2 += w6 * bflo(g6.y); a3 += w6 * bfhi(g6.y);
        a0 += w7 * bflo(g7.x); a1 += w7 * bfhi(g7.x); a2 += w7 * bflo(g7.y); a3 += w7 * bfhi(g7.y);
        ra = na; rb = nb2;
    }

    float v0 = 0.9f * a0 + bflo(x0[0]);
    float v1 = 0.9f * a1 + bfhi(x0[0]);
    float v2 = 0.9f * a2 + bflo(x0[1]);
    float v3 = 0.9f * a3 + bfhi(x0[1]);
    if (relu) {
        v0 = fmaxf(v0, 0.f); v1 = fmaxf(v1, 0.f);
        v2 = fmaxf(v2, 0.f); v3 = fmaxf(v3, 0.f);
    }
    uintx2 o; o[0] = pack2(v0, v1); o[1] = pack2(v2, v3);
    ntstore2(Xout + 2 * (pu2 + (size_t)node * 8 + j), o);
}

// ---------- head: logits = H @ Wc + bc ; log_softmax. 16 lanes/node ----------
// H in plane layout: plane p holds features [32p, 32p+32).
__global__ void head_kernel(const unsigned* __restrict__ Hb, const float* __restrict__ Wc,
                            const float* __restrict__ bc, float* __restrict__ out, int n) {
    int t = threadIdx.x;
    int o = t & (NOUT - 1);
    int node = blockIdx.x * (256 / NOUT) + (t >> 4);
    if (node >= n) return;
    const size_t pstride = (size_t)n * 16;
    float acc = bc[o];
    #pragma unroll
    for (int p = 0; p < 4; ++p) {
        const uint4* hp = (const uint4*)(Hb + (size_t)p * pstride + (size_t)node * 16);
        #pragma unroll
        for (int q = 0; q < 4; ++q) {
            uint4 u = hp[q];
            int k = p * 32 + q * 8;
            acc += bflo(u.x) * Wc[(k + 0) * NOUT + o];
            acc += bfhi(u.x) * Wc[(k + 1) * NOUT + o];
            acc += bflo(u.y) * Wc[(k + 2) * NOUT + o];
            acc += bfhi(u.y) * Wc[(k + 3) * NOUT + o];
            acc += bflo(u.z) * Wc[(k + 4) * NOUT + o];
            acc += bfhi(u.z) * Wc[(k + 5) * NOUT + o];
            acc += bflo(u.w) * Wc[(k + 6) * NOUT + o];
            acc += bfhi(u.w) * Wc[(k + 7) * NOUT + o];
        }
    }
    float m = acc;
    #pragma unroll
    for (int d = NOUT / 2; d > 0; d >>= 1) m = fmaxf(m, __shfl_xor(m, d, NOUT));
    float ex = __expf(acc - m);
    float s = ex;
    #pragma unroll
    for (int d = NOUT / 2; d > 0; d >>= 1) s += __shfl_xor(s, d, NOUT);
    out[node * NOUT + o] = acc - m - __logf(s);
}

// ---------- launch ----------

static inline size_t align256(size_t x) { return (x + 255) & ~(size_t)255; }

extern "C" void kernel_launch(void* const* d_in, const int* in_sizes, int n_in,
                              void* d_out, int out_size, void* d_ws, size_t ws_size,
                              hipStream_t stream) {
    const float* x  = (const float*)d_in[0];
    const int*   ei = (const int*)d_in[1];
    const float* W1 = (const float*)d_in[2];
    const float* b1 = (const float*)d_in[3];
    const float* W2 = (const float*)d_in[4];
    const float* b2 = (const float*)d_in[5];
    const float* W3 = (const float*)d_in[6];
    const float* b3 = (const float*)d_in[7];
    const float* Wc = (const float*)d_in[8];
    const float* bc = (const float*)d_in[9];
    float* out = (float*)d_out;

    const int n = in_sizes[0] / FD;       // 50000
    const int e = in_sizes[1] / 2;        // 800000
    const int nnz_max = e + n + 8 * n + 16;   // padded upper bound
    const int nb = (n + 1023) / 1024;

    const int* rows = ei;
    const int* cols = ei + e;

    // workspace layout (~57 MB)
    char* p = (char*)d_ws;
    int*      off  = (int*)p;       p += align256((size_t)(n + 1) * 4);
    int*      cur  = (int*)p;       p += align256((size_t)n * 4);
    float*    dinv = (float*)p;     p += align256((size_t)n * 4);
    int*      bsum = (int*)p;       p += align256((size_t)nb * 4);
    unsigned* eg   = (unsigned*)p;  p += align256((size_t)nnz_max * 4);
    unsigned* Wt   = (unsigned*)p;  p += align256((size_t)3 * 8192 * 4);
    unsigned* Ab   = (unsigned*)p;  p += align256((size_t)n * 64 * 4);
    unsigned* Bb   = (unsigned*)p;  p += align256((size_t)n * 64 * 4);
    unsigned* Z0b  = (unsigned*)p;  p += align256((size_t)n * 64 * 4);
    unsigned* Hb   = (unsigned*)p;  p += align256((size_t)n * 64 * 4);

    // ---- build padded CSC ----
    hipMemsetAsync(cur, 0, (size_t)n * 4, stream);
    hipMemsetAsync(eg, 0, (size_t)nnz_max * 4, stream);
    count_kernel<<<(e + 255) / 256, 256, 0, stream>>>(cols, cur, e);
    dinv_kernel<<<(n + 255) / 256, 256, 0, stream>>>(cur, dinv, n);
    scan_partial_kernel<<<nb, 256, 0, stream>>>(cur, bsum, n);
    scan_base_kernel<<<1, 64, 0, stream>>>(bsum, off, nb, n);
    scan_final_kernel<<<nb, 256, 0, stream>>>(cur, bsum, off, cur, n);
    fill_edges_kernel<<<(e + 255) / 256, 256, 0, stream>>>(rows, cols, dinv, cur, eg, e);
    fill_loops_kernel<<<(n + 255) / 256, 256, 0, stream>>>(dinv, cur, eg, n);

    // ---- weight transpose ----
    wtrans_kernel<<<32, 256, 0, stream>>>(W1, Wt);
    wtrans_kernel<<<32, 256, 0, stream>>>(W2, Wt + 8192);
    wtrans_kernel<<<32, 256, 0, stream>>>(W3, Wt + 16384);

    const int gemm_grid = (n + 63) / 64;
    const int spmm_grid = ((n + 31) / 32) * 4;    // 4 planes x 32-node chunks
    const float* bl[3] = { b1, b2, b3 };
    const void* gin = x;

    for (int st = 0; st < 3; ++st) {
        if (st == 0)
            gemm_mfma_kernel<0><<<gemm_grid, 256, 0, stream>>>(gin, Wt, bl[st], Ab, Z0b, n);
        else
            gemm_mfma_kernel<1><<<gemm_grid, 256, 0, stream>>>(gin, Wt + st * 8192, bl[st], Ab, Z0b, n);
        unsigned* bufs[2] = { Ab, Bb };
        int cu = 0;
        for (int k = 0; k < 10; ++k) {
            unsigned* o_ = (k == 9) ? Hb : bufs[cu ^ 1];
            spmm_plane_kernel<<<spmm_grid, 256, 0, stream>>>(off, eg, bufs[cu], Z0b, o_, n, k == 9);
            cu ^= 1;
        }
        gin = Hb;
    }

    head_kernel<<<(n + 15) / 16, 256, 0, stream>>>(Hb, Wc, bc, out, n);
}

// Round 13
// 1110.153 us; speedup vs baseline: 1.3303x; 1.0770x over previous
//
#include <hip/hip_runtime.h>
#include <math.h>

#define FD 128
#define NOUT 16
#define ALPHA_F 0.1f

typedef short short8 __attribute__((ext_vector_type(8)));
typedef float f32x4 __attribute__((ext_vector_type(4)));

// ---------- bf16 helpers (bit-level, RNE) ----------
__device__ __forceinline__ float bflo(unsigned u) { return __uint_as_float(u << 16); }
__device__ __forceinline__ float bfhi(unsigned u) { return __uint_as_float(u & 0xffff0000u); }
__device__ __forceinline__ unsigned f2bf(float f) {
    unsigned u = __float_as_uint(f);
    u += 0x7fffu + ((u >> 16) & 1u);          // round-to-nearest-even
    return u >> 16;
}
__device__ __forceinline__ unsigned pack2(float a, float b) {
    return f2bf(a) | (f2bf(b) << 16);
}

// ---------- CSC build ----------

__global__ void count_kernel(const int* __restrict__ cols, int* __restrict__ cnt, int e) {
    int i = blockIdx.x * blockDim.x + threadIdx.x;
    if (i < e) atomicAdd(&cnt[cols[i]], 1);
}

__global__ void dinv_kernel(const int* __restrict__ cnt, float* __restrict__ dinv, int n) {
    int i = blockIdx.x * blockDim.x + threadIdx.x;
    if (i < n) dinv[i] = rsqrtf((float)(cnt[i] + 1));   // +1 self-loop
}

// padded degree: true degree (cnt+1) rounded up to multiple of 8
__device__ __forceinline__ int padded(int cnt) { return (cnt + 8) & ~7; }

// three-kernel exclusive scan of padded degrees
__global__ void scan_partial_kernel(const int* __restrict__ cnt, int* __restrict__ bsum, int n) {
    __shared__ int sh[256];
    int base = blockIdx.x * 1024 + threadIdx.x * 4;
    int s = 0;
    #pragma unroll
    for (int j = 0; j < 4; ++j) { int i = base + j; if (i < n) s += padded(cnt[i]); }
    sh[threadIdx.x] = s; __syncthreads();
    for (int d = 128; d > 0; d >>= 1) {
        if ((int)threadIdx.x < d) sh[threadIdx.x] += sh[threadIdx.x + d];
        __syncthreads();
    }
    if (threadIdx.x == 0) bsum[blockIdx.x] = sh[0];
}

__global__ void scan_base_kernel(int* __restrict__ bsum, int* __restrict__ off, int nb, int n) {
    if (threadIdx.x == 0 && blockIdx.x == 0) {
        int run = 0;
        for (int b = 0; b < nb; ++b) { int t = bsum[b]; bsum[b] = run; run += t; }
        off[n] = run;
    }
}

// writes off[i] and cur[i]=off[i]. cnt and cur alias (read-before-write per thread).
__global__ void scan_final_kernel(const int* __restrict__ cnt, const int* __restrict__ bsum,
                                  int* __restrict__ off, int* __restrict__ cur, int n) {
    __shared__ int sh[256];
    int t = threadIdx.x;
    int base_i = blockIdx.x * 1024 + t * 4;
    int v[4]; int s = 0;
    #pragma unroll
    for (int j = 0; j < 4; ++j) { int i = base_i + j; v[j] = (i < n) ? padded(cnt[i]) : 0; s += v[j]; }
    sh[t] = s; __syncthreads();
    for (int d = 1; d < 256; d <<= 1) {
        int x = (t >= d) ? sh[t - d] : 0;
        __syncthreads();
        sh[t] += x;
        __syncthreads();
    }
    int excl = sh[t] - s + bsum[blockIdx.x];
    #pragma unroll
    for (int j = 0; j < 4; ++j) {
        int i = base_i + j;
        if (i < n) { off[i] = excl; cur[i] = excl; }
        excl += v[j];
    }
}

// edge record: low16 = src node id, high16 = bf16 weight
__global__ void fill_edges_kernel(const int* __restrict__ rows, const int* __restrict__ cols,
                                  const float* __restrict__ dinv, int* __restrict__ cur,
                                  unsigned* __restrict__ eg, int e) {
    int i = blockIdx.x * blockDim.x + threadIdx.x;
    if (i < e) {
        int r = rows[i];
        int c = cols[i];
        int pos = atomicAdd(&cur[c], 1);
        eg[pos] = (f2bf(dinv[r] * dinv[c]) << 16) | (unsigned)r;
    }
}

__global__ void fill_loops_kernel(const float* __restrict__ dinv, int* __restrict__ cur,
                                  unsigned* __restrict__ eg, int n) {
    int i = blockIdx.x * blockDim.x + threadIdx.x;
    if (i < n) {
        int pos = atomicAdd(&cur[i], 1);
        eg[pos] = (f2bf(dinv[i] * dinv[i]) << 16) | (unsigned)i;
    }
}

// ---------- pre-processing for MFMA GEMM ----------

// Wt[c][ku] = pack2(W[2ku][c], W[2ku+1][c]) : transposed, bf16-packed. 128x64 uints.
__global__ void wtrans_kernel(const float* __restrict__ W, unsigned* __restrict__ Wt) {
    int idx = blockIdx.x * 256 + threadIdx.x;
    if (idx < 128 * 64) {
        int c = idx >> 6, ku = idx & 63;
        Wt[idx] = pack2(W[(2 * ku) * FD + c], W[(2 * ku + 1) * FD + c]);
    }
}

// ---------- MFMA GEMM:  Y = X@W + b ; Ab = bf16(Y), Z0b = bf16(alpha*Y) ----------
// BF_IN=0: A read from fp32 (stage 1, RNE in-register convert); BF_IN=1: packed bf16.
template <int BF_IN>
__global__ __launch_bounds__(256, 4)
void gemm_mfma_kernel(const void* __restrict__ Xv, const unsigned* __restrict__ Wt,
                      const float* __restrict__ bias,
                      unsigned* __restrict__ Ab, unsigned* __restrict__ Z0b, int n) {
    int l = threadIdx.x & 63;
    int w = threadIdx.x >> 6;
    int l15 = l & 15, lq = l >> 4;
    int r0 = blockIdx.x * 64 + w * 16;
    int arow = min(r0 + l15, n - 1);
    const unsigned* bptr = Wt + (size_t)l15 * 64 + lq * 4;

    f32x4 acc[8];
    #pragma unroll
    for (int nt = 0; nt < 8; ++nt) acc[nt] = (f32x4){0.f, 0.f, 0.f, 0.f};

    #pragma unroll
    for (int kk = 0; kk < 4; ++kk) {
        short8 af;
        if (BF_IN) {
            const unsigned* aptr = (const unsigned*)Xv + (size_t)arow * 64 + lq * 4;
            af = *(const short8*)(aptr + kk * 16);
        } else {
            const float* ap = (const float*)Xv + (size_t)arow * FD + lq * 8 + kk * 32;
            float4 fa = *(const float4*)(ap);
            float4 fb = *(const float4*)(ap + 4);
            unsigned p0 = pack2(fa.x, fa.y), p1 = pack2(fa.z, fa.w);
            unsigned p2 = pack2(fb.x, fb.y), p3 = pack2(fb.z, fb.w);
            uint4 u = make_uint4(p0, p1, p2, p3);
            af = *(const short8*)&u;
        }
        #pragma unroll
        for (int nt = 0; nt < 8; ++nt) {
            short8 bf = *(const short8*)(bptr + nt * 1024 + kk * 16);
            acc[nt] = __builtin_amdgcn_mfma_f32_16x16x32_bf16(af, bf, acc[nt], 0, 0, 0);
        }
    }

    #pragma unroll
    for (int nt = 0; nt < 8; ++nt) {
        float b_ = bias[nt * 16 + l15];
        #pragma unroll
        for (int j = 0; j < 4; ++j) {
            float v = acc[nt][j] + b_;
            float vp = __shfl_xor(v, 1);
            int row = r0 + lq * 4 + j;
            if (!(l & 1) && row < n) {
                int cu = nt * 8 + (l15 >> 1);
                Ab[(size_t)row * 64 + cu]  = pack2(v, vp);
                Z0b[(size_t)row * 64 + cu] = pack2(ALPHA_F * v, ALPHA_F * vp);
            }
        }
    }
}

// ---------- APPNP step: Xout = 0.9*A_hat@Xin + Z0b, fp32 accum ----------
// 2 nodes per wave (32 lanes each, uint2 = 4 bf16 features per lane).
// Padded degrees (mult of 8, zero-weight pads) -> aligned uint4 record loads.
// 8 gathers in flight; fits the 64-VGPR cap at 8 waves/SIMD (no spill).
__global__ __launch_bounds__(256, 8)
void spmm_bf16_kernel(const int* __restrict__ off, const unsigned* __restrict__ eg,
                      const unsigned* __restrict__ Xin, const unsigned* __restrict__ X0b,
                      unsigned* __restrict__ Xout, int n, int relu) {
    int node = blockIdx.x * 8 + ((int)threadIdx.x >> 5);
    if (node >= n) return;
    int lane31 = threadIdx.x & 31;
    int s = off[node];
    int degpad = off[node + 1] - s;               // multiple of 8, >= 8
    int dother = __shfl_xor(degpad, 32);          // other half's degpad
    int dm = max(degpad, dother);
    const uint2* Xg = (const uint2*)Xin;
    uint2 x0 = ((const uint2*)X0b)[node * 32 + lane31];   // issue early
    float a0 = 0.f, a1 = 0.f, a2 = 0.f, a3 = 0.f;

    for (int base = 0; base < dm; base += 8) {
        int p = s + min(base, degpad - 8);
        bool live = base < degpad;                // beyond-own-end chunks masked
        uint4 ra = *(const uint4*)(eg + p);
        uint4 rb = *(const uint4*)(eg + p + 4);
        uint2 g0 = Xg[(ra.x & 0xffffu) * 32 + lane31];
        uint2 g1 = Xg[(ra.y & 0xffffu) * 32 + lane31];
        uint2 g2 = Xg[(ra.z & 0xffffu) * 32 + lane31];
        uint2 g3 = Xg[(ra.w & 0xffffu) * 32 + lane31];
        uint2 g4 = Xg[(rb.x & 0xffffu) * 32 + lane31];
        uint2 g5 = Xg[(rb.y & 0xffffu) * 32 + lane31];
        uint2 g6 = Xg[(rb.z & 0xffffu) * 32 + lane31];
        uint2 g7 = Xg[(rb.w & 0xffffu) * 32 + lane31];
        float w0 = live ? bfhi(ra.x) : 0.f;
        float w1 = live ? bfhi(ra.y) : 0.f;
        float w2 = live ? bfhi(ra.z) : 0.f;
        float w3 = live ? bfhi(ra.w) : 0.f;
        float w4 = live ? bfhi(rb.x) : 0.f;
        float w5 = live ? bfhi(rb.y) : 0.f;
        float w6 = live ? bfhi(rb.z) : 0.f;
        float w7 = live ? bfhi(rb.w) : 0.f;
        a0 += w0 * bflo(g0.x); a1 += w0 * bfhi(g0.x); a2 += w0 * bflo(g0.y); a3 += w0 * bfhi(g0.y);
        a0 += w1 * bflo(g1.x); a1 += w1 * bfhi(g1.x); a2 += w1 * bflo(g1.y); a3 += w1 * bfhi(g1.y);
        a0 += w2 * bflo(g2.x); a1 += w2 * bfhi(g2.x); a2 += w2 * bflo(g2.y); a3 += w2 * bfhi(g2.y);
        a0 += w3 * bflo(g3.x); a1 += w3 * bfhi(g3.x); a2 += w3 * bflo(g3.y); a3 += w3 * bfhi(g3.y);
        a0 += w4 * bflo(g4.x); a1 += w4 * bfhi(g4.x); a2 += w4 * bflo(g4.y); a3 += w4 * bfhi(g4.y);
        a0 += w5 * bflo(g5.x); a1 += w5 * bfhi(g5.x); a2 += w5 * bflo(g5.y); a3 += w5 * bfhi(g5.y);
        a0 += w6 * bflo(g6.x); a1 += w6 * bfhi(g6.x); a2 += w6 * bflo(g6.y); a3 += w6 * bfhi(g6.y);
        a0 += w7 * bflo(g7.x); a1 += w7 * bfhi(g7.x); a2 += w7 * bflo(g7.y); a3 += w7 * bfhi(g7.y);
    }

    float v0 = 0.9f * a0 + bflo(x0.x);
    float v1 = 0.9f * a1 + bfhi(x0.x);
    float v2 = 0.9f * a2 + bflo(x0.y);
    float v3 = 0.9f * a3 + bfhi(x0.y);
    if (relu) {
        v0 = fmaxf(v0, 0.f); v1 = fmaxf(v1, 0.f);
        v2 = fmaxf(v2, 0.f); v3 = fmaxf(v3, 0.f);
    }
    ((uint2*)Xout)[node * 32 + lane31] = make_uint2(pack2(v0, v1), pack2(v2, v3));
}

// ---------- head: logits = H @ Wc + bc ; log_softmax. 16 lanes/node ----------
__global__ void head_kernel(const unsigned* __restrict__ Hb, const float* __restrict__ Wc,
                            const float* __restrict__ bc, float* __restrict__ out, int n) {
    int t = threadIdx.x;
    int o = t & (NOUT - 1);
    int node = blockIdx.x * (256 / NOUT) + (t >> 4);
    if (node >= n) return;
    float acc = bc[o];
    const uint4* hrow = (const uint4*)(Hb + (size_t)node * 64);
    #pragma unroll 4
    for (int k4 = 0; k4 < 16; ++k4) {
        uint4 u = hrow[k4];
        int k = k4 * 8;
        acc += bflo(u.x) * Wc[(k + 0) * NOUT + o];
        acc += bfhi(u.x) * Wc[(k + 1) * NOUT + o];
        acc += bflo(u.y) * Wc[(k + 2) * NOUT + o];
        acc += bfhi(u.y) * Wc[(k + 3) * NOUT + o];
        acc += bflo(u.z) * Wc[(k + 4) * NOUT + o];
        acc += bfhi(u.z) * Wc[(k + 5) * NOUT + o];
        acc += bflo(u.w) * Wc[(k + 6) * NOUT + o];
        acc += bfhi(u.w) * Wc[(k + 7) * NOUT + o];
    }
    float m = acc;
    #pragma unroll
    for (int d = NOUT / 2; d > 0; d >>= 1) m = fmaxf(m, __shfl_xor(m, d, NOUT));
    float ex = __expf(acc - m);
    float s = ex;
    #pragma unroll
    for (int d = NOUT / 2; d > 0; d >>= 1) s += __shfl_xor(s, d, NOUT);
    out[node * NOUT + o] = acc - m - __logf(s);
}

// ---------- launch ----------

static inline size_t align256(size_t x) { return (x + 255) & ~(size_t)255; }

extern "C" void kernel_launch(void* const* d_in, const int* in_sizes, int n_in,
                              void* d_out, int out_size, void* d_ws, size_t ws_size,
                              hipStream_t stream) {
    const float* x  = (const float*)d_in[0];
    const int*   ei = (const int*)d_in[1];
    const float* W1 = (const float*)d_in[2];
    const float* b1 = (const float*)d_in[3];
    const float* W2 = (const float*)d_in[4];
    const float* b2 = (const float*)d_in[5];
    const float* W3 = (const float*)d_in[6];
    const float* b3 = (const float*)d_in[7];
    const float* Wc = (const float*)d_in[8];
    const float* bc = (const float*)d_in[9];
    float* out = (float*)d_out;

    const int n = in_sizes[0] / FD;       // 50000
    const int e = in_sizes[1] / 2;        // 800000
    const int nnz_max = e + n + 8 * n + 16;   // padded upper bound
    const int nb = (n + 1023) / 1024;

    const int* rows = ei;
    const int* cols = ei + e;

    // workspace layout (~57 MB)
    char* p = (char*)d_ws;
    int*      off  = (int*)p;       p += align256((size_t)(n + 1) * 4);
    int*      cur  = (int*)p;       p += align256((size_t)n * 4);
    float*    dinv = (float*)p;     p += align256((size_t)n * 4);
    int*      bsum = (int*)p;       p += align256((size_t)nb * 4);
    unsigned* eg   = (unsigned*)p;  p += align256((size_t)nnz_max * 4);
    unsigned* Wt   = (unsigned*)p;  p += align256((size_t)3 * 8192 * 4);
    unsigned* Ab   = (unsigned*)p;  p += align256((size_t)n * 64 * 4);
    unsigned* Bb   = (unsigned*)p;  p += align256((size_t)n * 64 * 4);
    unsigned* Z0b  = (unsigned*)p;  p += align256((size_t)n * 64 * 4);
    unsigned* Hb   = (unsigned*)p;  p += align256((size_t)n * 64 * 4);

    // ---- build padded CSC ----
    hipMemsetAsync(cur, 0, (size_t)n * 4, stream);
    hipMemsetAsync(eg, 0, (size_t)nnz_max * 4, stream);
    count_kernel<<<(e + 255) / 256, 256, 0, stream>>>(cols, cur, e);
    dinv_kernel<<<(n + 255) / 256, 256, 0, stream>>>(cur, dinv, n);
    scan_partial_kernel<<<nb, 256, 0, stream>>>(cur, bsum, n);
    scan_base_kernel<<<1, 64, 0, stream>>>(bsum, off, nb, n);
    scan_final_kernel<<<nb, 256, 0, stream>>>(cur, bsum, off, cur, n);
    fill_edges_kernel<<<(e + 255) / 256, 256, 0, stream>>>(rows, cols, dinv, cur, eg, e);
    fill_loops_kernel<<<(n + 255) / 256, 256, 0, stream>>>(dinv, cur, eg, n);

    // ---- weight transpose ----
    wtrans_kernel<<<32, 256, 0, stream>>>(W1, Wt);
    wtrans_kernel<<<32, 256, 0, stream>>>(W2, Wt + 8192);
    wtrans_kernel<<<32, 256, 0, stream>>>(W3, Wt + 16384);

    const int gemm_grid = (n + 63) / 64;
    const int spmm_grid = (n + 7) / 8;
    const float* bl[3] = { b1, b2, b3 };
    const void* gin = x;

    for (int st = 0; st < 3; ++st) {
        if (st == 0)
            gemm_mfma_kernel<0><<<gemm_grid, 256, 0, stream>>>(gin, Wt, bl[st], Ab, Z0b, n);
        else
            gemm_mfma_kernel<1><<<gemm_grid, 256, 0, stream>>>(gin, Wt + st * 8192, bl[st], Ab, Z0b, n);
        unsigned* bufs[2] = { Ab, Bb };
        int cu = 0;
        for (int k = 0; k < 10; ++k) {
            unsigned* o_ = (k == 9) ? Hb : bufs[cu ^ 1];
            spmm_bf16_kernel<<<spmm_grid, 256, 0, stream>>>(off, eg, bufs[cu], Z0b, o_, n, k == 9);
            cu ^= 1;
        }
        gin = Hb;
    }

    head_kernel<<<(n + 15) / 16, 256, 0, stream>>>(Hb, Wc, bc, out, n);
}